// Round 7
// baseline (38.078 us; speedup 1.0000x reference)
//
#include <hip/hip_runtime.h>
#include <math.h>

#define KPOOL 16
#define SPLIT 8  // threads per graph; 8 graphs per wave

typedef float f32x4 __attribute__((ext_vector_type(4)));

__device__ __forceinline__ void ce(float& x, float& y) {
  float hi = fmaxf(x, y), lo = fminf(x, y);
  x = hi;
  y = lo;
}

// Batcher odd-even mergesort, 8 inputs, 19 CEs, descending.
__device__ __forceinline__ void sort8(float (&v)[8]) {
  ce(v[0], v[1]); ce(v[2], v[3]); ce(v[4], v[5]); ce(v[6], v[7]);
  ce(v[0], v[2]); ce(v[1], v[3]); ce(v[4], v[6]); ce(v[5], v[7]);
  ce(v[1], v[2]); ce(v[5], v[6]);
  ce(v[0], v[4]); ce(v[1], v[5]); ce(v[2], v[6]); ce(v[3], v[7]);
  ce(v[2], v[4]); ce(v[3], v[5]);
  ce(v[1], v[2]); ce(v[3], v[4]); ce(v[5], v[6]);
}

// t sorted-16 desc, b sorted-8 desc -> t = top-16 of union, sorted.
__device__ __forceinline__ void merge8into16(float (&t)[KPOOL], const float (&b)[8]) {
#pragma unroll
  for (int i = 8; i < 16; ++i) t[i] = fmaxf(t[i], b[15 - i]);
#pragma unroll
  for (int s = 8; s >= 1; s >>= 1) {
#pragma unroll
    for (int i = 0; i < 16; ++i)
      if ((i & s) == 0) ce(t[i], t[i + s]);
  }
}

// Merge this lane's sorted-16 with lane^dist's: top-16 of union.
__device__ __forceinline__ void merge_partner(float (&t)[KPOOL], int dist) {
  float c[KPOOL];
#pragma unroll
  for (int i = 0; i < KPOOL; ++i) {
    float o = __shfl_xor(t[KPOOL - 1 - i], dist);
    c[i] = fmaxf(t[i], o);
  }
#pragma unroll
  for (int s = 8; s >= 1; s >>= 1) {
#pragma unroll
    for (int i = 0; i < KPOOL; ++i)
      if ((i & s) == 0) ce(c[i], c[i + s]);
  }
#pragma unroll
  for (int i = 0; i < KPOOL; ++i) t[i] = c[i];
}

__device__ __forceinline__ int lb_range(const int* __restrict__ a, int lo,
                                        int hi, int key) {
  while (lo < hi) {
    int mid = (lo + hi) >> 1;
    if (a[mid] < key) lo = mid + 1;
    else hi = mid;
  }
  return lo;
}

// Exact lower_bound with interpolation head-start: 1 probe at expected
// position, linear correction by mean spacing, verified +-512 window
// (>=5 sigma of residual), full-range binary fallback (exactness guaranteed).
__device__ __forceinline__ int lb_interp(const int* __restrict__ a, int total,
                                         int n, int key) {
  if (key <= 0) return 0;
  if (key >= n) return total;
  long long E = (long long)key * total / n;
  if (E > total - 1) E = total - 1;
  int v0 = a[(int)E];
  long long p1 = E + (long long)(key - v0) * total / n;
  int lo = (int)(p1 - 512 < 0 ? 0 : p1 - 512);
  int hi = (int)(p1 + 512 > total ? (long long)total : p1 + 512);
  bool ok = (lo == 0 || a[lo - 1] < key) && (hi == total || a[hi] >= key);
  if (!ok) { lo = 0; hi = total; }
  return lb_range(a, lo, hi, key);
}

__global__ __launch_bounds__(256, 6)
void sortpool_fused(const float* __restrict__ Y, const float* __restrict__ W,
                    const int* __restrict__ emap, float* __restrict__ out,
                    int total, int n) {
  const int tid = blockIdx.x * 256 + threadIdx.x;
  const int lane = threadIdx.x & 63;
  const int g = tid >> 3;         // this thread's graph
  const int q = tid & 7;          // chunk id within graph
  const int gj = lane >> 3;       // graph index within wave (0..7)
  const int g0 = (tid >> 6) << 3; // wave's first graph
  const bool valid = (g < n);

  // ---- prologue A: lanes 0..8 search the wave's 9 segment boundaries ----
  int bd = 0;
  {
    int key = g0 + lane;
    if (lane < 9 && key <= n) bd = lb_interp(emap, total, n, key);
  }
  int s0 = __shfl(bd, gj);
  int s1 = __shfl(bd, gj + 1);
  if (!valid) { s0 = 0; s1 = 0; }

  // ---- prologue B: softmax(W) across lanes 0..15 (once per wave) ----
  float wn_l;
  {
    float w = (lane < KPOOL) ? W[lane] : -INFINITY;
    float m = w;
#pragma unroll
    for (int d = 1; d < KPOOL; d <<= 1) m = fmaxf(m, __shfl_xor(m, d));
    float e = (lane < KPOOL) ? expf(w - m) : 0.0f;
    float s = e;
#pragma unroll
    for (int d = 1; d < KPOOL; d <<= 1) s += __shfl_xor(s, d);
    wn_l = e / s;  // lane k<16 holds softmax(W)[k]
  }

  const unsigned len = (unsigned)(s1 - s0);
  const int B0 = s0 >> 3;
  const int B1 = (s1 + 7) >> 3;
  const int BMAX = (total >> 3) - 1;  // clamp so every 32B load is in-bounds

  float t[KPOOL];
#pragma unroll
  for (int i = 0; i < KPOOL; ++i) t[i] = -INFINITY;

  // ---- scan: 16 elements (2 aligned 8-blocks) per iteration, 1-deep prefetch
  int b = B0 + 2 * q;
  f32x4 c0 = 0, c1 = 0, c2 = 0, c3 = 0;
  if (b < B1) {
    const f32x4* pA = reinterpret_cast<const f32x4*>(Y + (b << 3));
    int bB = b + 1 < BMAX ? b + 1 : BMAX;
    const f32x4* pB = reinterpret_cast<const f32x4*>(Y + (bB << 3));
    c0 = pA[0]; c1 = pA[1]; c2 = pB[0]; c3 = pB[1];
  }
#pragma unroll 1
  while (b < B1) {
    const int bn = b + 2 * SPLIT;
    f32x4 p0 = 0, p1 = 0, p2 = 0, p3 = 0;
    if (bn < B1) {  // prefetch next pair BEFORE consuming current
      const f32x4* pA = reinterpret_cast<const f32x4*>(Y + (bn << 3));
      int bB = bn + 1 < BMAX ? bn + 1 : BMAX;
      const f32x4* pB = reinterpret_cast<const f32x4*>(Y + (bB << 3));
      p0 = pA[0]; p1 = pA[1]; p2 = pB[0]; p3 = pB[1];
    }
    const int base = b << 3;
    {
      float v[8] = {c0[0], c0[1], c0[2], c0[3], c1[0], c1[1], c1[2], c1[3]};
#pragma unroll
      for (int jj = 0; jj < 8; ++jj)
        if ((unsigned)(base + jj - s0) >= len) v[jj] = -INFINITY;
      sort8(v);
      merge8into16(t, v);
    }
    {
      float u[8] = {c2[0], c2[1], c2[2], c2[3], c3[0], c3[1], c3[2], c3[3]};
#pragma unroll
      for (int jj = 0; jj < 8; ++jj)
        if ((unsigned)(base + 8 + jj - s0) >= len) u[jj] = -INFINITY;
      sort8(u);
      merge8into16(t, u);
    }
    c0 = p0; c1 = p1; c2 = p2; c3 = p3;
    b = bn;
  }

  // ---- combine the 8 chunks' sorted-16 lists (butterfly within 8 lanes) ----
  merge_partner(t, 1);
  merge_partner(t, 2);
  merge_partner(t, 4);

  // ---- weighted sum: Wn[k] broadcast from lane k (static shfl sources) ----
  float res = 0.0f;
#pragma unroll
  for (int k = 0; k < KPOOL; ++k) {
    float wk = __shfl(wn_l, k);
    float tv = t[k];
    res += (tv > -INFINITY) ? tv * wk : 0.0f;  // -inf (exhausted) -> 0
  }

  if (valid && q == 0) out[g] = res;
}

extern "C" void kernel_launch(void* const* d_in, const int* in_sizes, int n_in,
                              void* d_out, int out_size, void* d_ws, size_t ws_size,
                              hipStream_t stream) {
  const float* Y = (const float*)d_in[0];   // [TOTAL]
  const float* W = (const float*)d_in[1];   // [16]
  const int* emap = (const int*)d_in[2];    // [TOTAL], sorted
  const int total = in_sizes[0];
  const int n = in_sizes[3];                // len(v_count)
  float* out = (float*)d_out;               // [N] float32

  long long threads = (long long)n * SPLIT;
  int blocks = (int)((threads + 255) / 256);
  sortpool_fused<<<blocks, 256, 0, stream>>>(Y, W, emap, out, total, n);
}

// Round 8
// 37.499 us; speedup vs baseline: 1.0154x; 1.0154x over previous
//
#include <hip/hip_runtime.h>
#include <math.h>

#define KPOOL 16
#define SPLIT 8  // threads cooperating on one graph

typedef float f32x4 __attribute__((ext_vector_type(4)));

__device__ __forceinline__ void ce(float& x, float& y) {
  float hi = fmaxf(x, y), lo = fminf(x, y);
  x = hi;
  y = lo;
}

// Batcher odd-even mergesort, 8 inputs, 19 CEs, descending.
__device__ __forceinline__ void sort8(float (&v)[8]) {
  ce(v[0], v[1]); ce(v[2], v[3]); ce(v[4], v[5]); ce(v[6], v[7]);
  ce(v[0], v[2]); ce(v[1], v[3]); ce(v[4], v[6]); ce(v[5], v[7]);
  ce(v[1], v[2]); ce(v[5], v[6]);
  ce(v[0], v[4]); ce(v[1], v[5]); ce(v[2], v[6]); ce(v[3], v[7]);
  ce(v[2], v[4]); ce(v[3], v[5]);
  ce(v[1], v[2]); ce(v[3], v[4]); ce(v[5], v[6]);
}

// t sorted-16 desc, b sorted-8 desc -> t = top-16 of union, sorted.
__device__ __forceinline__ void merge8into16(float (&t)[KPOOL], const float (&b)[8]) {
#pragma unroll
  for (int i = 8; i < 16; ++i) t[i] = fmaxf(t[i], b[15 - i]);
#pragma unroll
  for (int s = 8; s >= 1; s >>= 1) {
#pragma unroll
    for (int i = 0; i < 16; ++i)
      if ((i & s) == 0) ce(t[i], t[i + s]);
  }
}

// Merge this lane's sorted-16 with lane^dist's: top-16 of union.
__device__ __forceinline__ void merge_partner(float (&t)[KPOOL], int dist) {
  float c[KPOOL];
#pragma unroll
  for (int i = 0; i < KPOOL; ++i) {
    float o = __shfl_xor(t[KPOOL - 1 - i], dist);
    c[i] = fmaxf(t[i], o);
  }
#pragma unroll
  for (int s = 8; s >= 1; s >>= 1) {
#pragma unroll
    for (int i = 0; i < KPOOL; ++i)
      if ((i & s) == 0) ce(c[i], c[i + s]);
  }
#pragma unroll
  for (int i = 0; i < KPOOL; ++i) t[i] = c[i];
}

__device__ __forceinline__ int lb_range(const int* __restrict__ a, int lo,
                                        int hi, int key) {
  while (lo < hi) {
    int mid = (lo + hi) >> 1;
    if (a[mid] < key) lo = mid + 1;
    else hi = mid;
  }
  return lo;
}

// Exact lower_bound via batched 8-ary search: window +-16384 (8 sigma of the
// Binomial boundary distribution) around the interpolated position; each round
// issues 7 INDEPENDENT probes (one waitcnt), narrowing 8x. 5 rounds + final
// probe = 7 exposed latencies total (incl. verify). Full-range fallback keeps
// exactness for the ~1e-4 tail.
__global__ __launch_bounds__(256)
void boundary_kernel(const int* __restrict__ emap, int total, int n,
                     int* __restrict__ starts, float* __restrict__ wn_out,
                     const float* __restrict__ W) {
  const int g = blockIdx.x * 256 + threadIdx.x;
  if (g == 0) {  // softmax(W), grid-uniform
    float w[KPOOL], m = -INFINITY, s = 0.0f;
#pragma unroll
    for (int k = 0; k < KPOOL; ++k) { w[k] = W[k]; m = fmaxf(m, w[k]); }
#pragma unroll
    for (int k = 0; k < KPOOL; ++k) { w[k] = expf(w[k] - m); s += w[k]; }
#pragma unroll
    for (int k = 0; k < KPOOL; ++k) wn_out[k] = w[k] / s;
  }
  if (g > n) return;
  if (g == 0) { starts[0] = 0; return; }       // e_map values >= 0
  if (g >= n) { starts[n] = total; return; }   // e_map values < n

  const int key = g;
  const int W0 = 32768;
  if (total < W0) { starts[g] = lb_range(emap, 0, total, key); return; }

  long long E = (long long)key * total / n;
  int wlo = (int)(E - W0 / 2);
  if (wlo < 0) wlo = 0;
  if (wlo > total - W0) wlo = total - W0;

  // round 1 (stride 4096) + verify, all loads independent
  int p[7];
#pragma unroll
  for (int k = 0; k < 7; ++k) p[k] = emap[wlo + (k + 1) * 4096];
  const int vlo = (wlo > 0) ? emap[wlo - 1] : (key - 1) - key;  // force "< key"
  const int vhi = emap[wlo + W0 - 1];
  const bool ok = (vlo < key) && ((wlo + W0 == total) || (vhi >= key));
  if (!ok) { starts[g] = lb_range(emap, 0, total, key); return; }

  int lo = wlo;
  int c = 0;
#pragma unroll
  for (int k = 0; k < 7; ++k) c += (p[k] < key) ? 1 : 0;
  lo += c * 4096;

  // rounds 2..5: strides 512, 64, 8, 1
#pragma unroll
  for (int w8 = 512; w8 >= 1; w8 >>= 3) {
#pragma unroll
    for (int k = 0; k < 7; ++k) p[k] = emap[lo + (k + 1) * w8];
    c = 0;
#pragma unroll
    for (int k = 0; k < 7; ++k) c += (p[k] < key) ? 1 : 0;
    lo += c * w8;
  }
  // answer in [lo, lo+1]
  starts[g] = (emap[lo] < key) ? lo + 1 : lo;
}

__global__ __launch_bounds__(256, 4)
void sortpool_main(const float* __restrict__ Y,
                   const int* __restrict__ starts,
                   const float* __restrict__ Wn,
                   float* __restrict__ out, int total, int n) {
  const int tid = blockIdx.x * 256 + threadIdx.x;
  const int g = tid >> 3;  // graph id; 8 consecutive lanes share a graph
  const int q = tid & 7;   // stride id
  if (g >= n) return;

  const int s0 = starts[g];
  const int s1 = starts[g + 1];
  const unsigned len = (unsigned)(s1 - s0);

  // Segment owns absolute 8-element blocks [B0, B1); every load is an aligned
  // 32B pair of float4s; partial coverage handled by one range compare/elem.
  const int B0 = s0 >> 3;
  const int B1 = (s1 + 7) >> 3;
  const int BLAST = (total >> 3) - 1;

  float t[KPOOL];
#pragma unroll
  for (int i = 0; i < KPOOL; ++i) t[i] = -INFINITY;

  // 1-deep software pipeline with UNCONDITIONAL clamped prefetch: the load is
  // never control-dependent, so the compiler cannot sink it to the use point
  // (round-7 pathology: VGPR=36 proved conditional prefetch was deleted).
  int b = B0 + q;
  {
    const int a0 = b <= BLAST ? b : BLAST;
    const f32x4* p = reinterpret_cast<const f32x4*>(Y + (a0 << 3));
    f32x4 c0 = p[0];
    f32x4 c1 = p[1];
#pragma unroll 1
    while (b < B1) {
      const int bn = b + SPLIT;
      const int an = bn < B1 ? bn : b;  // tail: re-read L1-hot current line
      const f32x4* pn = reinterpret_cast<const f32x4*>(Y + (an << 3));
      f32x4 n0 = pn[0];   // issued before consuming current batch
      f32x4 n1 = pn[1];
      const int base = b << 3;
      float v[8] = {c0[0], c0[1], c0[2], c0[3], c1[0], c1[1], c1[2], c1[3]};
#pragma unroll
      for (int jj = 0; jj < 8; ++jj) {
        // valid iff s0 <= base+jj < s1, as one unsigned compare
        if ((unsigned)(base + jj - s0) >= len) v[jj] = -INFINITY;
      }
      sort8(v);
      merge8into16(t, v);
      c0 = n0;
      c1 = n1;
      b = bn;
    }
  }

  // combine the 8 strides' sorted-16 lists (butterfly; all lanes equal)
  merge_partner(t, 1);
  merge_partner(t, 2);
  merge_partner(t, 4);

  // weighted sum with precomputed softmax(W); -inf slots (exhausted) -> 0
  float res = 0.0f;
#pragma unroll
  for (int k = 0; k < KPOOL; ++k) {
    float tv = t[k];
    res += (tv > -INFINITY) ? tv * Wn[k] : 0.0f;
  }

  if (q == 0) out[g] = res;
}

// Fallback main (no workspace): per-thread full binary search, same scan.
__global__ __launch_bounds__(256, 4)
void sortpool_main_nows(const float* __restrict__ Y, const float* __restrict__ W,
                        const int* __restrict__ emap, float* __restrict__ out,
                        int total, int n) {
  const int tid = blockIdx.x * 256 + threadIdx.x;
  const int g = tid >> 3;
  const int q = tid & 7;
  if (g >= n) return;
  const int s0 = lb_range(emap, 0, total, g);
  const int s1 = lb_range(emap, 0, total, g + 1);
  const unsigned len = (unsigned)(s1 - s0);
  const int B0 = s0 >> 3;
  const int B1 = (s1 + 7) >> 3;
  const int BLAST = (total >> 3) - 1;
  float t[KPOOL];
#pragma unroll
  for (int i = 0; i < KPOOL; ++i) t[i] = -INFINITY;
  int b = B0 + q;
  const int a0 = b <= BLAST ? b : BLAST;
  const f32x4* p = reinterpret_cast<const f32x4*>(Y + (a0 << 3));
  f32x4 c0 = p[0], c1 = p[1];
#pragma unroll 1
  while (b < B1) {
    const int bn = b + SPLIT;
    const int an = bn < B1 ? bn : b;
    const f32x4* pn = reinterpret_cast<const f32x4*>(Y + (an << 3));
    f32x4 n0 = pn[0], n1 = pn[1];
    const int base = b << 3;
    float v[8] = {c0[0], c0[1], c0[2], c0[3], c1[0], c1[1], c1[2], c1[3]};
#pragma unroll
    for (int jj = 0; jj < 8; ++jj)
      if ((unsigned)(base + jj - s0) >= len) v[jj] = -INFINITY;
    sort8(v);
    merge8into16(t, v);
    c0 = n0; c1 = n1; b = bn;
  }
  merge_partner(t, 1);
  merge_partner(t, 2);
  merge_partner(t, 4);
  float wv[KPOOL], m = -INFINITY, s = 0.0f;
#pragma unroll
  for (int k = 0; k < KPOOL; ++k) { wv[k] = W[k]; m = fmaxf(m, wv[k]); }
#pragma unroll
  for (int k = 0; k < KPOOL; ++k) { wv[k] = expf(wv[k] - m); s += wv[k]; }
  const float inv = 1.0f / s;
  float res = 0.0f;
#pragma unroll
  for (int k = 0; k < KPOOL; ++k) {
    float tv = t[k];
    res += (tv > -INFINITY) ? tv * (wv[k] * inv) : 0.0f;
  }
  if (q == 0) out[g] = res;
}

extern "C" void kernel_launch(void* const* d_in, const int* in_sizes, int n_in,
                              void* d_out, int out_size, void* d_ws, size_t ws_size,
                              hipStream_t stream) {
  const float* Y = (const float*)d_in[0];   // [TOTAL]
  const float* W = (const float*)d_in[1];   // [16]
  const int* emap = (const int*)d_in[2];    // [TOTAL], sorted
  const int total = in_sizes[0];
  const int n = in_sizes[3];                // len(v_count)
  float* out = (float*)d_out;               // [N] float32

  int* starts = (int*)d_ws;
  float* wn_buf = (float*)((char*)d_ws + (size_t)(n + 1) * sizeof(int));
  const bool use_ws =
      (ws_size >= (size_t)(n + 1) * sizeof(int) + KPOOL * sizeof(float));

  long long threads = (long long)n * SPLIT;
  int blocks = (int)((threads + 255) / 256);

  if (use_ws) {
    int nb = (n + 1 + 255) / 256;
    boundary_kernel<<<nb, 256, 0, stream>>>(emap, total, n, starts, wn_buf, W);
    sortpool_main<<<blocks, 256, 0, stream>>>(Y, starts, wn_buf, out, total, n);
  } else {
    sortpool_main_nows<<<blocks, 256, 0, stream>>>(Y, W, emap, out, total, n);
  }
}

// Round 9
// 33.529 us; speedup vs baseline: 1.1357x; 1.1184x over previous
//
#include <hip/hip_runtime.h>
#include <math.h>

#define KPOOL 16
#define SPLIT 2  // threads cooperating on one graph (long streams: ~16 batches)

typedef float f32x4 __attribute__((ext_vector_type(4)));

__device__ __forceinline__ void ce(float& x, float& y) {
  float hi = fmaxf(x, y), lo = fminf(x, y);
  x = hi;
  y = lo;
}

// Batcher odd-even mergesort, 8 inputs, 19 CEs, descending.
__device__ __forceinline__ void sort8(float (&v)[8]) {
  ce(v[0], v[1]); ce(v[2], v[3]); ce(v[4], v[5]); ce(v[6], v[7]);
  ce(v[0], v[2]); ce(v[1], v[3]); ce(v[4], v[6]); ce(v[5], v[7]);
  ce(v[1], v[2]); ce(v[5], v[6]);
  ce(v[0], v[4]); ce(v[1], v[5]); ce(v[2], v[6]); ce(v[3], v[7]);
  ce(v[2], v[4]); ce(v[3], v[5]);
  ce(v[1], v[2]); ce(v[3], v[4]); ce(v[5], v[6]);
}

// t sorted-16 desc, b sorted-8 desc -> t = top-16 of union, sorted.
__device__ __forceinline__ void merge8into16(float (&t)[KPOOL], const float (&b)[8]) {
#pragma unroll
  for (int i = 8; i < 16; ++i) t[i] = fmaxf(t[i], b[15 - i]);
#pragma unroll
  for (int s = 8; s >= 1; s >>= 1) {
#pragma unroll
    for (int i = 0; i < 16; ++i)
      if ((i & s) == 0) ce(t[i], t[i + s]);
  }
}

// Merge this lane's sorted-16 with lane^dist's: top-16 of union.
__device__ __forceinline__ void merge_partner(float (&t)[KPOOL], int dist) {
  float c[KPOOL];
#pragma unroll
  for (int i = 0; i < KPOOL; ++i) {
    float o = __shfl_xor(t[KPOOL - 1 - i], dist);
    c[i] = fmaxf(t[i], o);
  }
#pragma unroll
  for (int s = 8; s >= 1; s >>= 1) {
#pragma unroll
    for (int i = 0; i < KPOOL; ++i)
      if ((i & s) == 0) ce(c[i], c[i + s]);
  }
#pragma unroll
  for (int i = 0; i < KPOOL; ++i) t[i] = c[i];
}

__device__ __forceinline__ int lb_range(const int* __restrict__ a, int lo,
                                        int hi, int key) {
  while (lo < hi) {
    int mid = (lo + hi) >> 1;
    if (a[mid] < key) lo = mid + 1;
    else hi = mid;
  }
  return lo;
}

// Exact lower_bound via batched 8-ary search (7 independent probes/round over
// a +-16384 = 8-sigma verified window; full-range fallback for exactness).
__global__ __launch_bounds__(256)
void boundary_kernel(const int* __restrict__ emap, int total, int n,
                     int* __restrict__ starts, float* __restrict__ wn_out,
                     const float* __restrict__ W) {
  const int g = blockIdx.x * 256 + threadIdx.x;
  if (g == 0) {  // softmax(W), grid-uniform
    float w[KPOOL], m = -INFINITY, s = 0.0f;
#pragma unroll
    for (int k = 0; k < KPOOL; ++k) { w[k] = W[k]; m = fmaxf(m, w[k]); }
#pragma unroll
    for (int k = 0; k < KPOOL; ++k) { w[k] = expf(w[k] - m); s += w[k]; }
#pragma unroll
    for (int k = 0; k < KPOOL; ++k) wn_out[k] = w[k] / s;
  }
  if (g > n) return;
  if (g == 0) { starts[0] = 0; return; }       // e_map values >= 0
  if (g >= n) { starts[n] = total; return; }   // e_map values < n

  const int key = g;
  const int W0 = 32768;
  if (total < W0) { starts[g] = lb_range(emap, 0, total, key); return; }

  long long E = (long long)key * total / n;
  int wlo = (int)(E - W0 / 2);
  if (wlo < 0) wlo = 0;
  if (wlo > total - W0) wlo = total - W0;

  int p[7];
#pragma unroll
  for (int k = 0; k < 7; ++k) p[k] = emap[wlo + (k + 1) * 4096];
  const int vlo = (wlo > 0) ? emap[wlo - 1] : key - 1 - key;  // force "< key"
  const int vhi = emap[wlo + W0 - 1];
  const bool ok = (vlo < key) && ((wlo + W0 == total) || (vhi >= key));
  if (!ok) { starts[g] = lb_range(emap, 0, total, key); return; }

  int lo = wlo;
  int c = 0;
#pragma unroll
  for (int k = 0; k < 7; ++k) c += (p[k] < key) ? 1 : 0;
  lo += c * 4096;

#pragma unroll
  for (int w8 = 512; w8 >= 1; w8 >>= 3) {
#pragma unroll
    for (int k = 0; k < 7; ++k) p[k] = emap[lo + (k + 1) * w8];
    c = 0;
#pragma unroll
    for (int k = 0; k < 7; ++k) c += (p[k] < key) ? 1 : 0;
    lo += c * w8;
  }
  starts[g] = (emap[lo] < key) ? lo + 1 : lo;
}

__global__ __launch_bounds__(256, 4)
void sortpool_main(const float* __restrict__ Y,
                   const int* __restrict__ starts,
                   const float* __restrict__ Wn,
                   float* __restrict__ out, int total, int n) {
  const int tid = blockIdx.x * 256 + threadIdx.x;
  const int g = tid >> 1;  // graph id; 2 consecutive lanes share a graph
  const int q = tid & 1;   // stride id
  if (g >= n) return;

  const int s0 = starts[g];
  const int s1 = starts[g + 1];

  // Segment owns absolute 8-element blocks [B0, B1); all loads are aligned
  // 32B float4-pairs, clamped into [0, BLAST] so they are never OOB.
  const int B0 = s0 >> 3;
  const int B1 = (s1 + 7) >> 3;
  const int BLAST = (total >> 3) - 1;

  float t[KPOOL];
#pragma unroll
  for (int i = 0; i < KPOOL; ++i) t[i] = -INFINITY;

  // Depth-2 software pipeline, UNCONDITIONAL clamped prefetch (loads are never
  // control-dependent -> compiler cannot sink them; R7 lesson).
  int b = B0 + q;
  f32x4 c0, c1, m0, m1;
  {
    const int a0 = b <= BLAST ? b : BLAST;
    const f32x4* p = reinterpret_cast<const f32x4*>(Y + (a0 << 3));
    c0 = p[0]; c1 = p[1];
    const int b1 = b + SPLIT;
    const int a1 = b1 <= BLAST ? b1 : BLAST;
    const f32x4* p1 = reinterpret_cast<const f32x4*>(Y + (a1 << 3));
    m0 = p1[0]; m1 = p1[1];
  }
#pragma unroll 1
  while (b < B1) {
    const int b2 = b + 2 * SPLIT;
    const int a2 = b2 <= BLAST ? b2 : BLAST;
    const f32x4* p2 = reinterpret_cast<const f32x4*>(Y + (a2 << 3));
    f32x4 g0 = p2[0];  // issued before consuming current batch
    f32x4 g1 = p2[1];
    const int base = b << 3;
    float v[8] = {c0[0], c0[1], c0[2], c0[3], c1[0], c1[1], c1[2], c1[3]};
    if (base < s0 || base + 8 > s1) {  // only first/last block is partial
#pragma unroll
      for (int jj = 0; jj < 8; ++jj) {
        int idx = base + jj;
        if (idx < s0 || idx >= s1) v[jj] = -INFINITY;
      }
    }
    sort8(v);
    merge8into16(t, v);
    c0 = m0; c1 = m1; m0 = g0; m1 = g1;
    b += SPLIT;
  }

  // combine the 2 strides' sorted-16 lists (1 butterfly level)
  merge_partner(t, 1);

  // weighted sum with precomputed softmax(W); -inf slots (exhausted) -> 0
  float res = 0.0f;
#pragma unroll
  for (int k = 0; k < KPOOL; ++k) {
    float tv = t[k];
    res += (tv > -INFINITY) ? tv * Wn[k] : 0.0f;
  }

  if (q == 0) out[g] = res;
}

// Fallback main (no workspace): per-thread full binary search, same scan.
__global__ __launch_bounds__(256, 4)
void sortpool_main_nows(const float* __restrict__ Y, const float* __restrict__ W,
                        const int* __restrict__ emap, float* __restrict__ out,
                        int total, int n) {
  const int tid = blockIdx.x * 256 + threadIdx.x;
  const int g = tid >> 1;
  const int q = tid & 1;
  if (g >= n) return;
  const int s0 = lb_range(emap, 0, total, g);
  const int s1 = lb_range(emap, 0, total, g + 1);
  const int B0 = s0 >> 3;
  const int B1 = (s1 + 7) >> 3;
  const int BLAST = (total >> 3) - 1;
  float t[KPOOL];
#pragma unroll
  for (int i = 0; i < KPOOL; ++i) t[i] = -INFINITY;
  int b = B0 + q;
  f32x4 c0, c1, m0, m1;
  {
    const int a0 = b <= BLAST ? b : BLAST;
    const f32x4* p = reinterpret_cast<const f32x4*>(Y + (a0 << 3));
    c0 = p[0]; c1 = p[1];
    const int b1 = b + SPLIT;
    const int a1 = b1 <= BLAST ? b1 : BLAST;
    const f32x4* p1 = reinterpret_cast<const f32x4*>(Y + (a1 << 3));
    m0 = p1[0]; m1 = p1[1];
  }
#pragma unroll 1
  while (b < B1) {
    const int b2 = b + 2 * SPLIT;
    const int a2 = b2 <= BLAST ? b2 : BLAST;
    const f32x4* p2 = reinterpret_cast<const f32x4*>(Y + (a2 << 3));
    f32x4 g0 = p2[0];
    f32x4 g1 = p2[1];
    const int base = b << 3;
    float v[8] = {c0[0], c0[1], c0[2], c0[3], c1[0], c1[1], c1[2], c1[3]};
    if (base < s0 || base + 8 > s1) {
#pragma unroll
      for (int jj = 0; jj < 8; ++jj) {
        int idx = base + jj;
        if (idx < s0 || idx >= s1) v[jj] = -INFINITY;
      }
    }
    sort8(v);
    merge8into16(t, v);
    c0 = m0; c1 = m1; m0 = g0; m1 = g1;
    b += SPLIT;
  }
  merge_partner(t, 1);
  float wv[KPOOL], m = -INFINITY, s = 0.0f;
#pragma unroll
  for (int k = 0; k < KPOOL; ++k) { wv[k] = W[k]; m = fmaxf(m, wv[k]); }
#pragma unroll
  for (int k = 0; k < KPOOL; ++k) { wv[k] = expf(wv[k] - m); s += wv[k]; }
  const float inv = 1.0f / s;
  float res = 0.0f;
#pragma unroll
  for (int k = 0; k < KPOOL; ++k) {
    float tv = t[k];
    res += (tv > -INFINITY) ? tv * (wv[k] * inv) : 0.0f;
  }
  if (q == 0) out[g] = res;
}

extern "C" void kernel_launch(void* const* d_in, const int* in_sizes, int n_in,
                              void* d_out, int out_size, void* d_ws, size_t ws_size,
                              hipStream_t stream) {
  const float* Y = (const float*)d_in[0];   // [TOTAL]
  const float* W = (const float*)d_in[1];   // [16]
  const int* emap = (const int*)d_in[2];    // [TOTAL], sorted
  const int total = in_sizes[0];
  const int n = in_sizes[3];                // len(v_count)
  float* out = (float*)d_out;               // [N] float32

  int* starts = (int*)d_ws;
  float* wn_buf = (float*)((char*)d_ws + (size_t)(n + 1) * sizeof(int));
  const bool use_ws =
      (ws_size >= (size_t)(n + 1) * sizeof(int) + KPOOL * sizeof(float));

  long long threads = (long long)n * SPLIT;
  int blocks = (int)((threads + 255) / 256);

  if (use_ws) {
    int nb = (n + 1 + 255) / 256;
    boundary_kernel<<<nb, 256, 0, stream>>>(emap, total, n, starts, wn_buf, W);
    sortpool_main<<<blocks, 256, 0, stream>>>(Y, starts, wn_buf, out, total, n);
  } else {
    sortpool_main_nows<<<blocks, 256, 0, stream>>>(Y, W, emap, out, total, n);
  }
}